// Round 11
// baseline (585.566 us; speedup 1.0000x reference)
//
#include <hip/hip_runtime.h>
#include <math.h>

// Decoder_910533066914 — R11: k_step8 = 512 blocks(jb x bh) x 256 thr with
// CONTIGUOUS ping-pong h (R9's strided-A was the regression, not the split),
// 4-partial reduce, hoisted prep/cst loads, R10-verified gate butterfly.
// k_softmax register-resident (no 48KB LDS stage). Rest = R10.

typedef _Float16 fp16;
typedef __attribute__((ext_vector_type(8))) _Float16 fp16x8;
typedef __attribute__((ext_vector_type(4))) float f32x4;

constexpr int B = 32, T = 64, S = 64, D = 1024, A = 512, E = 256, L = 1024, V = 12000;
constexpr int G = 4096;
constexpr size_t N_PROBS = (size_t)B * T * V;

__device__ inline void load_lds16(const void* g, void* l) {
  __builtin_amdgcn_global_load_lds(
      (const __attribute__((address_space(1))) unsigned int*)g,
      (__attribute__((address_space(3))) unsigned int*)l, 16, 0, 0);
}

// ---------------- attention precompute ----------------

__global__ void k_v2(const float* __restrict__ W2, const float* __restrict__ Va,
                     float* __restrict__ v2) {
  int gw = (blockIdx.x * blockDim.x + threadIdx.x) >> 6;
  int lane = threadIdx.x & 63;
  if (gw >= D) return;
  float acc = 0.f;
  for (int a = lane; a < A; a += 64) acc += W2[(size_t)gw * A + a] * Va[a];
  #pragma unroll
  for (int off = 32; off; off >>= 1) acc += __shfl_down(acc, off);
  if (lane == 0) v2[gw] = acc;
}

__global__ void k_score(const float* __restrict__ options, const float* __restrict__ v2,
                        float* __restrict__ w) {
  int row = (blockIdx.x * blockDim.x + threadIdx.x) >> 6;
  int lane = threadIdx.x & 63;
  if (row >= B * S) return;
  const float* orow = options + (size_t)row * D;
  float acc = 0.f;
  for (int d = lane; d < D; d += 64) acc += orow[d] * v2[d];
  #pragma unroll
  for (int off = 32; off; off >>= 1) acc += __shfl_down(acc, off);
  if (lane == 0) w[row] = acc;
}

__global__ __launch_bounds__(256) void k_attnctx(
    const float* __restrict__ options, const float* __restrict__ wat,
    float* __restrict__ oattn, float* __restrict__ ctx) {
  __shared__ float sw[64];
  const int b = blockIdx.x, tid = threadIdx.x;
  if (tid < 64) {
    float v = wat[b * 64 + tid];
    float m = v;
    #pragma unroll
    for (int off = 32; off; off >>= 1) m = fmaxf(m, __shfl_xor(m, off));
    float e = expf(v - m);
    float s = e;
    #pragma unroll
    for (int off = 32; off; off >>= 1) s += __shfl_xor(s, off);
    float res = e / s;
    sw[tid] = res;
    oattn[b * 64 + tid] = res;
  }
  __syncthreads();
  for (int d = tid; d < D; d += 256) {
    float acc = 0.f;
    #pragma unroll 8
    for (int s = 0; s < 64; ++s)
      acc += sw[s] * options[((size_t)(b * 64 + s)) * D + d];
    ctx[b * D + d] = acc;
  }
}

// ---------------- cx = bl + ctx@Wx1, split-K ----------------
__global__ __launch_bounds__(256) void k_cx_part(
    const float* __restrict__ ctx, const float* __restrict__ Wx,
    float* __restrict__ cxp) {
  const int jt = blockIdx.x & 15;
  const int bg = (blockIdx.x >> 4) & 3;
  const int kc = blockIdx.x >> 6;
  const int j = jt * 256 + threadIdx.x;
  const int b0 = bg * 8, d0 = kc * 128;
  float acc[8];
  #pragma unroll
  for (int bb = 0; bb < 8; ++bb) acc[bb] = 0.f;
  for (int d = 0; d < 128; ++d) {
    float wv = Wx[(size_t)(d0 + d) * G + j];
    #pragma unroll
    for (int bb = 0; bb < 8; ++bb)
      acc[bb] = fmaf(ctx[(b0 + bb) * D + d0 + d], wv, acc[bb]);
  }
  #pragma unroll
  for (int bb = 0; bb < 8; ++bb)
    cxp[((size_t)kc * 32 + b0 + bb) * G + j] = acc[bb];
}

__global__ void k_cx_reduce(const float* __restrict__ cxp, const float* __restrict__ bl,
                            float* __restrict__ cx) {
  int i = blockIdx.x * 256 + threadIdx.x;
  float s = bl[i & 4095];
  #pragma unroll
  for (int kc = 0; kc < 8; ++kc) s += cxp[(size_t)kc * 131072 + i];
  cx[i] = s;
}

// ---------------- gathers / transposes ----------------

__global__ void k_eg(const int* __restrict__ targets, const float* __restrict__ emb,
                     fp16* __restrict__ eg) {
  int r = blockIdx.x, e = threadIdx.x;
  int tok = targets[r];
  eg[(size_t)r * E + e] = (fp16)emb[(size_t)tok * E + e];
}

__global__ __launch_bounds__(256) void k_wx2t(const float* __restrict__ Wx,
                                              fp16* __restrict__ t16) {
  __shared__ float s[64][65];
  const int et = blockIdx.x >> 6, jt = blockIdx.x & 63;
  const int e0 = et * 64, j0 = jt * 64;
  const int tid = threadIdx.x;
  const int jj = tid & 63;
  #pragma unroll
  for (int k = 0; k < 16; ++k) {
    int ee = k * 4 + (tid >> 6);
    s[ee][jj] = Wx[(size_t)(D + e0 + ee) * G + j0 + jj];
  }
  __syncthreads();
  const int jc = tid >> 2, eq = tid & 3;
  fp16x8 o0, o1;
  #pragma unroll
  for (int i = 0; i < 8; ++i) {
    o0[i] = (fp16)s[eq * 16 + i][jc];
    o1[i] = (fp16)s[eq * 16 + 8 + i][jc];
  }
  size_t dst = (size_t)(j0 + jc) * E + e0 + eq * 16;
  *(fp16x8*)(t16 + dst) = o0;
  *(fp16x8*)(t16 + dst + 8) = o1;
}

// Whp[rowp][l] = Wh[l][col] fp16, rowp = (jj>>2)*16 + g*4 + (jj&3), col = g*1024+jj
__global__ __launch_bounds__(256) void k_whp(const float* __restrict__ Wh,
                                             fp16* __restrict__ p) {
  __shared__ float s[64][65];
  const int lt = blockIdx.x & 15, ct = blockIdx.x >> 4;
  const int l0 = lt * 64, c0 = ct * 64;
  const int tid = threadIdx.x;
  const int cc = tid & 63;
  #pragma unroll
  for (int k = 0; k < 16; ++k) {
    int ll = k * 4 + (tid >> 6);
    s[ll][cc] = Wh[(size_t)(l0 + ll) * G + c0 + cc];
  }
  __syncthreads();
  const int c = tid >> 2, lq = tid & 3;
  const int col = c0 + c, g = col >> 10, jj = col & 1023;
  const int rowp = ((jj >> 2) << 4) + (g << 2) + (jj & 3);
  fp16x8 o0, o1;
  #pragma unroll
  for (int i = 0; i < 8; ++i) {
    o0[i] = (fp16)s[lq * 16 + i][c];
    o1[i] = (fp16)s[lq * 16 + 8 + i][c];
  }
  size_t dst = (size_t)rowp * L + l0 + lq * 16;
  *(fp16x8*)(p + dst) = o0;
  *(fp16x8*)(p + dst + 8) = o1;
}

__global__ void k_h0split(const float* __restrict__ h0, const float* __restrict__ c0,
                          fp16* __restrict__ h16, float* __restrict__ cst) {
  int i = blockIdx.x * 256 + threadIdx.x;
  h16[i] = (fp16)h0[i];
  cst[i] = c0[i];
}

// ---------------- pre = Eg@Wx2t^T + cx -> prep[t][jb][b][jo*4+g] fp16 ---------
__global__ __launch_bounds__(256) void k_pre_mfma(
    const fp16* __restrict__ Ag, const fp16* __restrict__ Bg,
    const float* __restrict__ cx, fp16* __restrict__ prep) {
  __shared__ __align__(16) char lds[32768];
  char* sA = lds;
  char* sB = lds + 16384;
  const int bid = blockIdx.x;
  const int swz = (bid & 7) * 64 + (bid >> 3);
  const int mt = swz >> 5, nt = swz & 31;
  const int m0 = mt * 128, n0 = nt * 128;
  const int tid = threadIdx.x, w = tid >> 6, lane = tid & 63;
  const int wr = w >> 1, wc = w & 1;

  f32x4 acc[4][4];
  #pragma unroll
  for (int i = 0; i < 4; ++i)
    #pragma unroll
    for (int j = 0; j < 4; ++j) acc[i][j] = (f32x4){0.f, 0.f, 0.f, 0.f};

  int rowc[4], sloc[4];
  #pragma unroll
  for (int i = 0; i < 4; ++i) {
    int c = i * 4 + w;
    rowc[i] = c * 8 + (lane >> 3);
    sloc[i] = (lane & 7) ^ (rowc[i] & 7);
  }

  for (int kk = 0; kk < 4; ++kk) {
    if (kk) __syncthreads();
    const char* ga = (const char*)Ag + kk * 128;
    const char* gb = (const char*)Bg + kk * 128;
    #pragma unroll
    for (int i = 0; i < 4; ++i) {
      int c = i * 4 + w;
      load_lds16(ga + (size_t)(m0 + rowc[i]) * 512 + sloc[i] * 16, sA + c * 1024);
      load_lds16(gb + (size_t)(n0 + rowc[i]) * 512 + sloc[i] * 16, sB + c * 1024);
    }
    __syncthreads();
    #pragma unroll
    for (int ks = 0; ks < 2; ++ks) {
      fp16x8 av[4], bv[4];
      #pragma unroll
      for (int f = 0; f < 4; ++f) {
        int ra = wr * 64 + f * 16 + (lane & 15);
        int ca = (ks * 4 + (lane >> 4)) ^ (ra & 7);
        av[f] = *(const fp16x8*)(sA + ra * 128 + ca * 16);
        int rb = wc * 64 + f * 16 + (lane & 15);
        int cb = (ks * 4 + (lane >> 4)) ^ (rb & 7);
        bv[f] = *(const fp16x8*)(sB + rb * 128 + cb * 16);
      }
      #pragma unroll
      for (int fm = 0; fm < 4; ++fm)
        #pragma unroll
        for (int fn = 0; fn < 4; ++fn)
          acc[fm][fn] = __builtin_amdgcn_mfma_f32_16x16x32_f16(
              av[fm], bv[fn], acc[fm][fn], 0, 0, 0);
    }
  }

  const int r0o = m0 + wr * 64 + ((lane >> 4) << 2);
  const int c0o = n0 + wc * 64 + (lane & 15);
  #pragma unroll
  for (int fn = 0; fn < 4; ++fn) {
    int colg = c0o + fn * 16;
    int g = colg >> 10, jj = colg & 1023;
    int jb = jj >> 2, jo = jj & 3;
    #pragma unroll
    for (int fm = 0; fm < 4; ++fm) {
      #pragma unroll
      for (int r = 0; r < 4; ++r) {
        int row = r0o + fm * 16 + r;
        int b = row >> 6, t = row & 63;
        float v = acc[fm][fn][r] + cx[(size_t)b * G + colg];
        prep[(((size_t)t * 256 + jb) * 32 + b) * 16 + jo * 4 + g] = (fp16)v;
      }
    }
  }
}

// ---------------- recurrence step: 512 blocks (jb, bh) x 256 thr --------------
// Wave w: K slice [w*256,+256), 8 MFMAs/2 chains on CONTIGUOUS hin rows.
// One barrier; 256 threads each own one (b_local,col) z-cell; fast __expf;
// activated-gate butterfly (R10-verified); g==0 lanes write.
__global__ __launch_bounds__(256) void k_step8(
    const fp16* __restrict__ Whp, const fp16* __restrict__ prep,
    const fp16* __restrict__ hin, fp16* __restrict__ hout,
    float* __restrict__ cst, fp16* __restrict__ Hb16,
    float* __restrict__ out_h, float* __restrict__ out_c, int t) {
  __shared__ f32x4 zred[4][64]; // 4 KB
  const int jb = blockIdx.x >> 1, bh = blockIdx.x & 1;
  const int tid = threadIdx.x;
  const int w = tid >> 6, lane = tid & 63;
  const int fr = lane & 15, kc = lane >> 4;

  // post-phase loads hoisted above MFMA (in flight during compute)
  const int b_local = tid >> 4, col = tid & 15;
  const int b = bh * 16 + b_local;
  const int g = col >> 2, jo = col & 3;
  const int gj = jb * 4 + jo;
  const float pfv = (float)prep[(((size_t)t * 256 + jb) * 32 + b) * 16 + jo * 4 + g];
  const float cp = (g == 0) ? cst[b * 1024 + gj] : 0.f;

  f32x4 a0 = (f32x4){0.f, 0.f, 0.f, 0.f}, a1 = a0;
  const fp16* bb = Whp + (size_t)(jb * 16 + fr) * 1024 + w * 256 + kc * 8;
  const fp16* aa = hin + (size_t)(bh * 16 + fr) * 1024 + w * 256 + kc * 8;
  #pragma unroll
  for (int kk = 0; kk < 8; kk += 2) {
    a0 = __builtin_amdgcn_mfma_f32_16x16x32_f16(
        *(const fp16x8*)(aa + kk * 32), *(const fp16x8*)(bb + kk * 32), a0, 0, 0, 0);
    a1 = __builtin_amdgcn_mfma_f32_16x16x32_f16(
        *(const fp16x8*)(aa + (kk + 1) * 32), *(const fp16x8*)(bb + (kk + 1) * 32), a1, 0, 0, 0);
  }
  f32x4 zv;
  #pragma unroll
  for (int q = 0; q < 4; ++q) zv[q] = a0[q] + a1[q];
  zred[w][lane] = zv;
  __syncthreads();

  // one z per thread (C/D layout: col=lane&15, row=(lane>>4)*4+reg)
  const int lane2 = ((b_local >> 2) << 4) | col;
  const int reg = b_local & 3;
  float z = zred[0][lane2][reg] + zred[1][lane2][reg]
          + zred[2][lane2][reg] + zred[3][lane2][reg];
  z += pfv;
  // activate own gate (g==2: tanh, else sigmoid)
  float act;
  if (g == 2) act = 1.f - 2.f / (1.f + __expf(2.f * z));
  else        act = 1.f / (1.f + __expf(-z));
  // butterfly activated gates across lane bits 2,3 (= g)
  float x4 = __shfl_xor(act, 4);
  float za = (g & 1) ? x4 : act;   // gate (g & ~1)
  float zb = (g & 1) ? act : x4;   // gate (g | 1)
  float za2 = __shfl_xor(za, 8);
  float zb2 = __shfl_xor(zb, 8);
  const bool lo = (g < 2);
  float Ai = lo ? za : za2;   // sigmoid(i)
  float Af = lo ? zb : zb2;   // sigmoid(f)
  float Ag_ = lo ? za2 : za;  // tanh(g)
  float Ao = lo ? zb2 : zb;   // sigmoid(o)
  if (g == 0) {
    const int ci = b * 1024 + gj;
    float cn = Af * cp + Ai * Ag_;
    float th = 1.f - 2.f / (1.f + __expf(2.f * cn));
    float hn = Ao * th;
    cst[ci] = cn;
    hout[ci] = (fp16)hn;
    Hb16[((size_t)b * 64 + t) * 1024 + gj] = (fp16)hn;
    if (t == T - 1) {
      out_h[ci] = hn;
      out_c[ci] = cn;
    }
  }
}

// ---------------- Wd -> Wdt fp16 ----------------
__global__ __launch_bounds__(256) void k_wdt(const float* __restrict__ Wd,
                                             fp16* __restrict__ Wdt) {
  __shared__ float s[64][65];
  const int lt = blockIdx.x & 15;
  const int vt = blockIdx.x >> 4;
  const int l0 = lt * 64, v0 = vt * 64;
  const int tid = threadIdx.x;
  const int lv = tid & 63;
  #pragma unroll
  for (int k = 0; k < 16; ++k) {
    int ll = k * 4 + (tid >> 6);
    int v = v0 + lv;
    s[ll][lv] = (v < V) ? Wd[(size_t)(l0 + ll) * V + v] : 0.f;
  }
  __syncthreads();
  const int vv = tid >> 2, lq = tid & 3;
  fp16x8 o0, o1;
  #pragma unroll
  for (int j = 0; j < 8; ++j) {
    o0[j] = (fp16)s[lq * 16 + j][vv];
    o1[j] = (fp16)s[lq * 16 + 8 + j][vv];
  }
  fp16* dst = Wdt + (size_t)(v0 + vv) * 1024 + l0 + lq * 16;
  *(fp16x8*)dst = o0;
  *(fp16x8*)(dst + 8) = o1;
}

// ---------------- logits fp16 MFMA GEMM, 32KB LDS, two-pass epilogue ---------
__global__ __launch_bounds__(256) void k_logits_mfma(
    const fp16* __restrict__ Ag, const fp16* __restrict__ Btg,
    const float* __restrict__ bd, float* __restrict__ out) {
  __shared__ __align__(16) char lds[32768];
  char* sA = lds;
  char* sB = lds + 16384;
  const int bid = blockIdx.x;
  const int wg = (bid & 7) * 188 + (bid >> 3);
  const int nt = wg >> 4, mt = wg & 15;   // column-major XCD coverage
  const int m0 = mt * 128, n0 = nt * 128;
  const int tid = threadIdx.x, w = tid >> 6, lane = tid & 63;
  const int wr = w >> 1, wc = w & 1;

  f32x4 acc[4][4];
  #pragma unroll
  for (int i = 0; i < 4; ++i)
    #pragma unroll
    for (int j = 0; j < 4; ++j) acc[i][j] = (f32x4){0.f, 0.f, 0.f, 0.f};

  int rowc[4], sloc[4];
  #pragma unroll
  for (int i = 0; i < 4; ++i) {
    int c = i * 4 + w;
    rowc[i] = c * 8 + (lane >> 3);
    sloc[i] = (lane & 7) ^ (rowc[i] & 7);
  }

  for (int kk = 0; kk < 16; ++kk) {
    if (kk) __syncthreads();
    const char* ga = (const char*)Ag + kk * 128;
    const char* gb = (const char*)Btg + kk * 128;
    #pragma unroll
    for (int i = 0; i < 4; ++i) {
      int c = i * 4 + w;
      load_lds16(ga + (size_t)(m0 + rowc[i]) * 2048 + sloc[i] * 16, sA + c * 1024);
      load_lds16(gb + (size_t)(n0 + rowc[i]) * 2048 + sloc[i] * 16, sB + c * 1024);
    }
    __syncthreads();
    #pragma unroll
    for (int ks = 0; ks < 2; ++ks) {
      fp16x8 av[4], bv[4];
      #pragma unroll
      for (int f = 0; f < 4; ++f) {
        int ra = wr * 64 + f * 16 + (lane & 15);
        int ca = (ks * 4 + (lane >> 4)) ^ (ra & 7);
        av[f] = *(const fp16x8*)(sA + ra * 128 + ca * 16);
        int rb = wc * 64 + f * 16 + (lane & 15);
        int cb = (ks * 4 + (lane >> 4)) ^ (rb & 7);
        bv[f] = *(const fp16x8*)(sB + rb * 128 + cb * 16);
      }
      #pragma unroll
      for (int fm = 0; fm < 4; ++fm)
        #pragma unroll
        for (int fn = 0; fn < 4; ++fn)
          acc[fm][fn] = __builtin_amdgcn_mfma_f32_16x16x32_f16(
              av[fm], bv[fn], acc[fm][fn], 0, 0, 0);
    }
  }

  // two-pass epilogue: 64x128 fp32 half-tile in the 32KB LDS, coalesced out
  float* ctile = (float*)lds;
  float bvv[4];
  #pragma unroll
  for (int fn = 0; fn < 4; ++fn) {
    int colg = n0 + wc * 64 + fn * 16 + (lane & 15);
    bvv[fn] = (colg < V) ? bd[colg] : 0.f;
  }
  #pragma unroll
  for (int p = 0; p < 2; ++p) {
    __syncthreads();
    if (wr == p) {
      const int col = wc * 64 + (lane & 15);
      #pragma unroll
      for (int fn = 0; fn < 4; ++fn) {
        #pragma unroll
        for (int fm = 0; fm < 4; ++fm) {
          int row = fm * 16 + ((lane >> 4) << 2);
          #pragma unroll
          for (int r = 0; r < 4; ++r)
            ctile[(row + r) * 128 + col + fn * 16] = acc[fm][fn][r] + bvv[fn];
        }
      }
    }
    __syncthreads();
    #pragma unroll
    for (int it = 0; it < 8; ++it) {
      int idx = it * 256 + tid;
      int row = idx >> 5, ch = idx & 31;
      int colg = n0 + ch * 4;
      if (colg < V)
        *(float4*)&out[(size_t)(m0 + p * 64 + row) * V + colg] =
            *(float4*)&ctile[row * 128 + ch * 4];
    }
  }
}

// ---------------- row softmax (register-resident) ----------------
__global__ __launch_bounds__(256) void k_softmax(float* __restrict__ logits) {
  __shared__ float sred[4];
  float* row = logits + (size_t)blockIdx.x * V;
  const int tid = threadIdx.x;
  const float4* rv = (const float4*)row;
  float4 v[12];
  float m = -3.4e38f;
  #pragma unroll
  for (int k = 0; k < 12; ++k) {
    int i = tid + k * 256;
    if (i < 3000) {
      v[k] = rv[i];
      m = fmaxf(fmaxf(m, fmaxf(v[k].x, v[k].y)), fmaxf(v[k].z, v[k].w));
    }
  }
  #pragma unroll
  for (int off = 32; off; off >>= 1) m = fmaxf(m, __shfl_xor(m, off));
  if ((tid & 63) == 0) sred[tid >> 6] = m;
  __syncthreads();
  const float M = fmaxf(fmaxf(sred[0], sred[1]), fmaxf(sred[2], sred[3]));
  float s = 0.f;
  #pragma unroll
  for (int k = 0; k < 12; ++k) {
    int i = tid + k * 256;
    if (i < 3000) {
      v[k].x = __expf(v[k].x - M); v[k].y = __expf(v[k].y - M);
      v[k].z = __expf(v[k].z - M); v[k].w = __expf(v[k].w - M);
      s += v[k].x + v[k].y + v[k].z + v[k].w;
    }
  }
  #pragma unroll
  for (int off = 32; off; off >>= 1) s += __shfl_xor(s, off);
  __syncthreads();
  if ((tid & 63) == 0) sred[tid >> 6] = s;
  __syncthreads();
  const float inv = 1.f / (sred[0] + sred[1] + sred[2] + sred[3]);
  float4* ov = (float4*)row;
  #pragma unroll
  for (int k = 0; k < 12; ++k) {
    int i = tid + k * 256;
    if (i < 3000) {
      float4 x = v[k];
      x.x *= inv; x.y *= inv; x.z *= inv; x.w *= inv;
      ov[i] = x;
    }
  }
}

// ---------------- launch ----------------

extern "C" void kernel_launch(void* const* d_in, const int* in_sizes, int n_in,
                              void* d_out, int out_size, void* d_ws, size_t ws_size,
                              hipStream_t stream) {
  const int*   targets = (const int*)d_in[0];
  const float* options = (const float*)d_in[1];
  const float* h0      = (const float*)d_in[2];
  const float* c0      = (const float*)d_in[3];
  const float* emb     = (const float*)d_in[4];
  const float* W2      = (const float*)d_in[7];
  const float* Va      = (const float*)d_in[9];
  const float* Wx      = (const float*)d_in[11];
  const float* Wh      = (const float*)d_in[12];
  const float* bl      = (const float*)d_in[13];
  const float* Wd      = (const float*)d_in[14];
  const float* bd      = (const float*)d_in[15];

  float* out      = (float*)d_out;
  float* out_h    = out + N_PROBS;
  float* out_c    = out_h + (size_t)B * L;
  float* out_attn = out_c + (size_t)B * L;

  // ---- workspace layout (bytes), total ~31.1 MiB ----
  char* wsb = (char*)d_ws;
  float* v2     = (float*)(wsb);               // 4 KB
  float* wat    = (float*)(wsb + 4096);        // 8 KB
  float* ctx    = (float*)(wsb + 12288);       // 128 KB
  float* cx     = (float*)(wsb + 143360);      // 512 KB
  float* cst    = (float*)(wsb + 667648);      // 128 KB
  fp16*  hA     = (fp16*)(wsb + 798720);       // 64 KB
  fp16*  hB     = (fp16*)(wsb + 864256);       // 64 KB
  fp16*  Eg16   = (fp16*)(wsb + 1191936);      // 1 MB
  fp16*  Wx2t16 = (fp16*)(wsb + 2240512);      // 2 MB
  fp16*  Hb16   = (fp16*)(wsb + 1191936);      // alias X base, 4 MB (post pre-GEMM)
  fp16*  Whp    = (fp16*)(wsb + 7483392);      // 8 MB
  fp16*  prep   = (fp16*)(wsb + 15872000);     // 16 MB
  float* cxp    = (float*)(wsb + 15872000);    // alias prep (pre-GEMM phase only)
  fp16*  Wdt    = (fp16*)(wsb + 7483392);      // alias Whp+prep (post-recurrence)

  // attention (h-independent)
  k_v2<<<256, 256, 0, stream>>>(W2, Va, v2);
  k_score<<<512, 256, 0, stream>>>(options, v2, wat);
  k_attnctx<<<32, 256, 0, stream>>>(options, wat, out_attn, ctx);
  k_cx_part<<<512, 256, 0, stream>>>(ctx, Wx, cxp);
  k_cx_reduce<<<512, 256, 0, stream>>>(cxp, bl, cx);

  // transforms
  k_eg<<<2048, 256, 0, stream>>>(targets, emb, Eg16);
  k_wx2t<<<256, 256, 0, stream>>>(Wx, Wx2t16);
  k_whp<<<1024, 256, 0, stream>>>(Wh, Whp);

  // pre = Eg @ Wx2 + cx  (permuted prep layout)
  k_pre_mfma<<<512, 256, 0, stream>>>(Eg16, Wx2t16, cx, prep);
  k_h0split<<<128, 256, 0, stream>>>(h0, c0, hA, cst);

  // recurrence: per-step launches; finalize fused into t=63
  for (int t = 0; t < T; ++t) {
    const fp16* hin = (t & 1) ? hB : hA;
    fp16* hout = (t & 1) ? hA : hB;
    k_step8<<<512, 256, 0, stream>>>(Whp, prep, hin, hout, cst, Hb16,
                                     out_h, out_c, t);
  }

  // logits + softmax
  k_wdt<<<188 * 16, 256, 0, stream>>>(Wd, Wdt);
  k_logits_mfma<<<1504, 256, 0, stream>>>(Hb16, Wdt, bd, out);
  k_softmax<<<B * T, 256, 0, stream>>>(out);
}

// Round 14
// 547.415 us; speedup vs baseline: 1.0697x; 1.0697x over previous
//
#include <hip/hip_runtime.h>
#include <math.h>

// Decoder_910533066914 — R14: recombination of best VERIFIED pieces.
// Persistent-barrier branch abandoned (R12/R13 aborts: per-XCD L2 spin
// visibility not guaranteeable from HIP). k_step4 (R7, fastest measured step
// kernel) + finalize fused at t=63 (R10-verified) + 32KB two-pass logits
// (R10/R11, 61.5us) + register softmax (R11). Precompute unchanged.

typedef _Float16 fp16;
typedef __attribute__((ext_vector_type(8))) _Float16 fp16x8;
typedef __attribute__((ext_vector_type(4))) _Float16 fp16x4;
typedef __attribute__((ext_vector_type(4))) float f32x4;

constexpr int B = 32, T = 64, S = 64, D = 1024, A = 512, E = 256, L = 1024, V = 12000;
constexpr int G = 4096;
constexpr size_t N_PROBS = (size_t)B * T * V;

__device__ inline void load_lds16(const void* g, void* l) {
  __builtin_amdgcn_global_load_lds(
      (const __attribute__((address_space(1))) unsigned int*)g,
      (__attribute__((address_space(3))) unsigned int*)l, 16, 0, 0);
}

// ---------------- attention precompute ----------------

__global__ void k_v2(const float* __restrict__ W2, const float* __restrict__ Va,
                     float* __restrict__ v2) {
  int gw = (blockIdx.x * blockDim.x + threadIdx.x) >> 6;
  int lane = threadIdx.x & 63;
  if (gw >= D) return;
  float acc = 0.f;
  for (int a = lane; a < A; a += 64) acc += W2[(size_t)gw * A + a] * Va[a];
  #pragma unroll
  for (int off = 32; off; off >>= 1) acc += __shfl_down(acc, off);
  if (lane == 0) v2[gw] = acc;
}

__global__ void k_score(const float* __restrict__ options, const float* __restrict__ v2,
                        float* __restrict__ w) {
  int row = (blockIdx.x * blockDim.x + threadIdx.x) >> 6;
  int lane = threadIdx.x & 63;
  if (row >= B * S) return;
  const float* orow = options + (size_t)row * D;
  float acc = 0.f;
  for (int d = lane; d < D; d += 64) acc += orow[d] * v2[d];
  #pragma unroll
  for (int off = 32; off; off >>= 1) acc += __shfl_down(acc, off);
  if (lane == 0) w[row] = acc;
}

__global__ __launch_bounds__(256) void k_attnctx(
    const float* __restrict__ options, const float* __restrict__ wat,
    float* __restrict__ oattn, float* __restrict__ ctx) {
  __shared__ float sw[64];
  const int b = blockIdx.x, tid = threadIdx.x;
  if (tid < 64) {
    float v = wat[b * 64 + tid];
    float m = v;
    #pragma unroll
    for (int off = 32; off; off >>= 1) m = fmaxf(m, __shfl_xor(m, off));
    float e = expf(v - m);
    float s = e;
    #pragma unroll
    for (int off = 32; off; off >>= 1) s += __shfl_xor(s, off);
    float res = e / s;
    sw[tid] = res;
    oattn[b * 64 + tid] = res;
  }
  __syncthreads();
  for (int d = tid; d < D; d += 256) {
    float acc = 0.f;
    #pragma unroll 8
    for (int s = 0; s < 64; ++s)
      acc += sw[s] * options[((size_t)(b * 64 + s)) * D + d];
    ctx[b * D + d] = acc;
  }
}

// ---------------- cx = bl + ctx@Wx1, split-K ----------------
__global__ __launch_bounds__(256) void k_cx_part(
    const float* __restrict__ ctx, const float* __restrict__ Wx,
    float* __restrict__ cxp) {
  const int jt = blockIdx.x & 15;
  const int bg = (blockIdx.x >> 4) & 3;
  const int kc = blockIdx.x >> 6;
  const int j = jt * 256 + threadIdx.x;
  const int b0 = bg * 8, d0 = kc * 128;
  float acc[8];
  #pragma unroll
  for (int bb = 0; bb < 8; ++bb) acc[bb] = 0.f;
  for (int d = 0; d < 128; ++d) {
    float wv = Wx[(size_t)(d0 + d) * G + j];
    #pragma unroll
    for (int bb = 0; bb < 8; ++bb)
      acc[bb] = fmaf(ctx[(b0 + bb) * D + d0 + d], wv, acc[bb]);
  }
  #pragma unroll
  for (int bb = 0; bb < 8; ++bb)
    cxp[((size_t)kc * 32 + b0 + bb) * G + j] = acc[bb];
}

__global__ void k_cx_reduce(const float* __restrict__ cxp, const float* __restrict__ bl,
                            float* __restrict__ cx) {
  int i = blockIdx.x * 256 + threadIdx.x;
  float s = bl[i & 4095];
  #pragma unroll
  for (int kc = 0; kc < 8; ++kc) s += cxp[(size_t)kc * 131072 + i];
  cx[i] = s;
}

// ---------------- gathers / transposes ----------------

__global__ void k_eg(const int* __restrict__ targets, const float* __restrict__ emb,
                     fp16* __restrict__ eg) {
  int r = blockIdx.x, e = threadIdx.x;
  int tok = targets[r];
  eg[(size_t)r * E + e] = (fp16)emb[(size_t)tok * E + e];
}

__global__ __launch_bounds__(256) void k_wx2t(const float* __restrict__ Wx,
                                              fp16* __restrict__ t16) {
  __shared__ float s[64][65];
  const int et = blockIdx.x >> 6, jt = blockIdx.x & 63;
  const int e0 = et * 64, j0 = jt * 64;
  const int tid = threadIdx.x;
  const int jj = tid & 63;
  #pragma unroll
  for (int k = 0; k < 16; ++k) {
    int ee = k * 4 + (tid >> 6);
    s[ee][jj] = Wx[(size_t)(D + e0 + ee) * G + j0 + jj];
  }
  __syncthreads();
  const int jc = tid >> 2, eq = tid & 3;
  fp16x8 o0, o1;
  #pragma unroll
  for (int i = 0; i < 8; ++i) {
    o0[i] = (fp16)s[eq * 16 + i][jc];
    o1[i] = (fp16)s[eq * 16 + 8 + i][jc];
  }
  size_t dst = (size_t)(j0 + jc) * E + e0 + eq * 16;
  *(fp16x8*)(t16 + dst) = o0;
  *(fp16x8*)(t16 + dst + 8) = o1;
}

// Whp[rowp][l] = Wh[l][col] fp16, rowp = (jj>>2)*16 + g*4 + (jj&3), col = g*1024+jj
__global__ __launch_bounds__(256) void k_whp(const float* __restrict__ Wh,
                                             fp16* __restrict__ p) {
  __shared__ float s[64][65];
  const int lt = blockIdx.x & 15, ct = blockIdx.x >> 4;
  const int l0 = lt * 64, c0 = ct * 64;
  const int tid = threadIdx.x;
  const int cc = tid & 63;
  #pragma unroll
  for (int k = 0; k < 16; ++k) {
    int ll = k * 4 + (tid >> 6);
    s[ll][cc] = Wh[(size_t)(l0 + ll) * G + c0 + cc];
  }
  __syncthreads();
  const int c = tid >> 2, lq = tid & 3;
  const int col = c0 + c, g = col >> 10, jj = col & 1023;
  const int rowp = ((jj >> 2) << 4) + (g << 2) + (jj & 3);
  fp16x8 o0, o1;
  #pragma unroll
  for (int i = 0; i < 8; ++i) {
    o0[i] = (fp16)s[lq * 16 + i][c];
    o1[i] = (fp16)s[lq * 16 + 8 + i][c];
  }
  size_t dst = (size_t)rowp * L + l0 + lq * 16;
  *(fp16x8*)(p + dst) = o0;
  *(fp16x8*)(p + dst + 8) = o1;
}

__global__ void k_h0split(const float* __restrict__ h0, const float* __restrict__ c0,
                          fp16* __restrict__ h16, float* __restrict__ cst) {
  int i = blockIdx.x * 256 + threadIdx.x;
  h16[i] = (fp16)h0[i];
  cst[i] = c0[i];
}

// ---------------- pre = Eg@Wx2t^T + cx -> prep[t][jb][b][jo*4+g] fp16 ---------
__global__ __launch_bounds__(256) void k_pre_mfma(
    const fp16* __restrict__ Ag, const fp16* __restrict__ Bg,
    const float* __restrict__ cx, fp16* __restrict__ prep) {
  __shared__ __align__(16) char lds[32768];
  char* sA = lds;
  char* sB = lds + 16384;
  const int bid = blockIdx.x;
  const int swz = (bid & 7) * 64 + (bid >> 3);
  const int mt = swz >> 5, nt = swz & 31;
  const int m0 = mt * 128, n0 = nt * 128;
  const int tid = threadIdx.x, w = tid >> 6, lane = tid & 63;
  const int wr = w >> 1, wc = w & 1;

  f32x4 acc[4][4];
  #pragma unroll
  for (int i = 0; i < 4; ++i)
    #pragma unroll
    for (int j = 0; j < 4; ++j) acc[i][j] = (f32x4){0.f, 0.f, 0.f, 0.f};

  int rowc[4], sloc[4];
  #pragma unroll
  for (int i = 0; i < 4; ++i) {
    int c = i * 4 + w;
    rowc[i] = c * 8 + (lane >> 3);
    sloc[i] = (lane & 7) ^ (rowc[i] & 7);
  }

  for (int kk = 0; kk < 4; ++kk) {
    if (kk) __syncthreads();
    const char* ga = (const char*)Ag + kk * 128;
    const char* gb = (const char*)Bg + kk * 128;
    #pragma unroll
    for (int i = 0; i < 4; ++i) {
      int c = i * 4 + w;
      load_lds16(ga + (size_t)(m0 + rowc[i]) * 512 + sloc[i] * 16, sA + c * 1024);
      load_lds16(gb + (size_t)(n0 + rowc[i]) * 512 + sloc[i] * 16, sB + c * 1024);
    }
    __syncthreads();
    #pragma unroll
    for (int ks = 0; ks < 2; ++ks) {
      fp16x8 av[4], bv[4];
      #pragma unroll
      for (int f = 0; f < 4; ++f) {
        int ra = wr * 64 + f * 16 + (lane & 15);
        int ca = (ks * 4 + (lane >> 4)) ^ (ra & 7);
        av[f] = *(const fp16x8*)(sA + ra * 128 + ca * 16);
        int rb = wc * 64 + f * 16 + (lane & 15);
        int cb = (ks * 4 + (lane >> 4)) ^ (rb & 7);
        bv[f] = *(const fp16x8*)(sB + rb * 128 + cb * 16);
      }
      #pragma unroll
      for (int fm = 0; fm < 4; ++fm)
        #pragma unroll
        for (int fn = 0; fn < 4; ++fn)
          acc[fm][fn] = __builtin_amdgcn_mfma_f32_16x16x32_f16(
              av[fm], bv[fn], acc[fm][fn], 0, 0, 0);
    }
  }

  const int r0o = m0 + wr * 64 + ((lane >> 4) << 2);
  const int c0o = n0 + wc * 64 + (lane & 15);
  #pragma unroll
  for (int fn = 0; fn < 4; ++fn) {
    int colg = c0o + fn * 16;
    int g = colg >> 10, jj = colg & 1023;
    int jb = jj >> 2, jo = jj & 3;
    #pragma unroll
    for (int fm = 0; fm < 4; ++fm) {
      #pragma unroll
      for (int r = 0; r < 4; ++r) {
        int row = r0o + fm * 16 + r;
        int b = row >> 6, t = row & 63;
        float v = acc[fm][fn][r] + cx[(size_t)b * G + colg];
        prep[(((size_t)t * 256 + jb) * 32 + b) * 16 + jo * 4 + g] = (fp16)v;
      }
    }
  }
}

// ---------------- recurrence step (R7's k_step4, finalize fused) --------------
// 256 blocks x 512 thr. Wave w: K slice [w*128,+128), m=0,1 b-halves; 8 MFMAs.
// Two-barrier 16-way LDS reduce + 128-thread gate tail (measured fastest).
__global__ __launch_bounds__(512) void k_step4(
    const fp16* __restrict__ Whp, const fp16* __restrict__ prep,
    const fp16* __restrict__ hin, fp16* __restrict__ hout,
    float* __restrict__ cst, fp16* __restrict__ Hb16,
    float* __restrict__ out_h, float* __restrict__ out_c, int t) {
  __shared__ float zred[8 * 2 * 64 * 4]; // 16 KB
  __shared__ float zf[32][16];           // 2 KB
  const int jb = blockIdx.x;
  const int tid = threadIdx.x;
  const int w = tid >> 6, lane = tid & 63;
  const int fr = lane & 15, kc = lane >> 4;

  // gate-phase prefetch (overlaps MFMA): one contiguous fp16x4 per thread
  float pf[4];
  float cprev = 0.f;
  const int gb = tid >> 2, gjo = tid & 3, gj = jb * 4 + gjo;
  if (tid < 128) {
    fp16x4 pv = *(const fp16x4*)(prep + (((size_t)t * 256 + jb) * 32 + gb) * 16 + gjo * 4);
    #pragma unroll
    for (int g = 0; g < 4; ++g) pf[g] = (float)pv[g];
    cprev = cst[gb * 1024 + gj];
  }

  f32x4 acc[2];
  acc[0] = (f32x4){0.f, 0.f, 0.f, 0.f};
  acc[1] = (f32x4){0.f, 0.f, 0.f, 0.f};
  const fp16* bb = Whp + (size_t)(jb * 16 + fr) * L;
  #pragma unroll
  for (int kk = 0; kk < 4; ++kk) {
    const int k0 = (w * 4 + kk) * 32 + kc * 8;
    fp16x8 bv = *(const fp16x8*)(bb + k0);
    #pragma unroll
    for (int m = 0; m < 2; ++m) {
      fp16x8 av = *(const fp16x8*)(hin + (size_t)(m * 16 + fr) * L + k0);
      acc[m] = __builtin_amdgcn_mfma_f32_16x16x32_f16(av, bv, acc[m], 0, 0, 0);
    }
  }
  #pragma unroll
  for (int m = 0; m < 2; ++m)
    *(f32x4*)&zred[((w * 2 + m) * 64 + lane) * 4] = acc[m];
  __syncthreads();
  {
    const int b = tid >> 4, c = tid & 15;
    const int lane2 = (((b & 15) >> 2) << 4) | c;
    const int reg = b & 3, m = b >> 4;
    float s = 0.f;
    #pragma unroll
    for (int ww = 0; ww < 8; ++ww)
      s += zred[((ww * 2 + m) * 64 + lane2) * 4 + reg];
    zf[b][c] = s;
  }
  __syncthreads();
  if (tid < 128) {
    float zi = zf[gb][gjo] + pf[0];
    float zff = zf[gb][4 + gjo] + pf[1];
    float zg = zf[gb][8 + gjo] + pf[2];
    float zo = zf[gb][12 + gjo] + pf[3];
    float si = 1.f / (1.f + expf(-zi));
    float sf = 1.f / (1.f + expf(-zff));
    float tg = tanhf(zg);
    float so = 1.f / (1.f + expf(-zo));
    float cn = sf * cprev + si * tg;
    float hn = so * tanhf(cn);
    const int hi_idx = gb * 1024 + gj;
    cst[hi_idx] = cn;
    hout[hi_idx] = (fp16)hn;
    Hb16[(size_t)(gb * 64 + t) * L + gj] = (fp16)hn;
    if (t == T - 1) {
      out_h[hi_idx] = hn;
      out_c[hi_idx] = cn;
    }
  }
}

// ---------------- Wd -> Wdt fp16 ----------------
__global__ __launch_bounds__(256) void k_wdt(const float* __restrict__ Wd,
                                             fp16* __restrict__ Wdt) {
  __shared__ float s[64][65];
  const int lt = blockIdx.x & 15;
  const int vt = blockIdx.x >> 4;
  const int l0 = lt * 64, v0 = vt * 64;
  const int tid = threadIdx.x;
  const int lv = tid & 63;
  #pragma unroll
  for (int k = 0; k < 16; ++k) {
    int ll = k * 4 + (tid >> 6);
    int v = v0 + lv;
    s[ll][lv] = (v < V) ? Wd[(size_t)(l0 + ll) * V + v] : 0.f;
  }
  __syncthreads();
  const int vv = tid >> 2, lq = tid & 3;
  fp16x8 o0, o1;
  #pragma unroll
  for (int j = 0; j < 8; ++j) {
    o0[j] = (fp16)s[lq * 16 + j][vv];
    o1[j] = (fp16)s[lq * 16 + 8 + j][vv];
  }
  fp16* dst = Wdt + (size_t)(v0 + vv) * 1024 + l0 + lq * 16;
  *(fp16x8*)dst = o0;
  *(fp16x8*)(dst + 8) = o1;
}

// ---------------- logits fp16 MFMA GEMM, 32KB LDS, two-pass epilogue ---------
__global__ __launch_bounds__(256) void k_logits_mfma(
    const fp16* __restrict__ Ag, const fp16* __restrict__ Btg,
    const float* __restrict__ bd, float* __restrict__ out) {
  __shared__ __align__(16) char lds[32768];
  char* sA = lds;
  char* sB = lds + 16384;
  const int bid = blockIdx.x;
  const int wg = (bid & 7) * 188 + (bid >> 3);
  const int nt = wg >> 4, mt = wg & 15;   // column-major XCD coverage
  const int m0 = mt * 128, n0 = nt * 128;
  const int tid = threadIdx.x, w = tid >> 6, lane = tid & 63;
  const int wr = w >> 1, wc = w & 1;

  f32x4 acc[4][4];
  #pragma unroll
  for (int i = 0; i < 4; ++i)
    #pragma unroll
    for (int j = 0; j < 4; ++j) acc[i][j] = (f32x4){0.f, 0.f, 0.f, 0.f};

  int rowc[4], sloc[4];
  #pragma unroll
  for (int i = 0; i < 4; ++i) {
    int c = i * 4 + w;
    rowc[i] = c * 8 + (lane >> 3);
    sloc[i] = (lane & 7) ^ (rowc[i] & 7);
  }

  for (int kk = 0; kk < 16; ++kk) {
    if (kk) __syncthreads();
    const char* ga = (const char*)Ag + kk * 128;
    const char* gb = (const char*)Btg + kk * 128;
    #pragma unroll
    for (int i = 0; i < 4; ++i) {
      int c = i * 4 + w;
      load_lds16(ga + (size_t)(m0 + rowc[i]) * 2048 + sloc[i] * 16, sA + c * 1024);
      load_lds16(gb + (size_t)(n0 + rowc[i]) * 2048 + sloc[i] * 16, sB + c * 1024);
    }
    __syncthreads();
    #pragma unroll
    for (int ks = 0; ks < 2; ++ks) {
      fp16x8 av[4], bv[4];
      #pragma unroll
      for (int f = 0; f < 4; ++f) {
        int ra = wr * 64 + f * 16 + (lane & 15);
        int ca = (ks * 4 + (lane >> 4)) ^ (ra & 7);
        av[f] = *(const fp16x8*)(sA + ra * 128 + ca * 16);
        int rb = wc * 64 + f * 16 + (lane & 15);
        int cb = (ks * 4 + (lane >> 4)) ^ (rb & 7);
        bv[f] = *(const fp16x8*)(sB + rb * 128 + cb * 16);
      }
      #pragma unroll
      for (int fm = 0; fm < 4; ++fm)
        #pragma unroll
        for (int fn = 0; fn < 4; ++fn)
          acc[fm][fn] = __builtin_amdgcn_mfma_f32_16x16x32_f16(
              av[fm], bv[fn], acc[fm][fn], 0, 0, 0);
    }
  }

  // two-pass epilogue: 64x128 fp32 half-tile in the 32KB LDS, coalesced out
  float* ctile = (float*)lds;
  float bvv[4];
  #pragma unroll
  for (int fn = 0; fn < 4; ++fn) {
    int colg = n0 + wc * 64 + fn * 16 + (lane & 15);
    bvv[fn] = (colg < V) ? bd[colg] : 0.f;
  }
  #pragma unroll
  for (int p = 0; p < 2; ++p) {
    __syncthreads();
    if (wr == p) {
      const int col = wc * 64 + (lane & 15);
      #pragma unroll
      for (int fn = 0; fn < 4; ++fn) {
        #pragma unroll
        for (int fm = 0; fm < 4; ++fm) {
          int row = fm * 16 + ((lane >> 4) << 2);
          #pragma unroll
          for (int r = 0; r < 4; ++r)
            ctile[(row + r) * 128 + col + fn * 16] = acc[fm][fn][r] + bvv[fn];
        }
      }
    }
    __syncthreads();
    #pragma unroll
    for (int it = 0; it < 8; ++it) {
      int idx = it * 256 + tid;
      int row = idx >> 5, ch = idx & 31;
      int colg = n0 + ch * 4;
      if (colg < V)
        *(float4*)&out[(size_t)(m0 + p * 64 + row) * V + colg] =
            *(float4*)&ctile[row * 128 + ch * 4];
    }
  }
}

// ---------------- row softmax (register-resident) ----------------
__global__ __launch_bounds__(256) void k_softmax(float* __restrict__ logits) {
  __shared__ float sred[4];
  float* row = logits + (size_t)blockIdx.x * V;
  const int tid = threadIdx.x;
  const float4* rv = (const float4*)row;
  float4 v[12];
  float m = -3.4e38f;
  #pragma unroll
  for (int k = 0; k < 12; ++k) {
    int i = tid + k * 256;
    if (i < 3000) {
      v[k] = rv[i];
      m = fmaxf(fmaxf(m, fmaxf(v[k].x, v[k].y)), fmaxf(v[k].z, v[k].w));
    }
  }
  #pragma unroll
  for (int off = 32; off; off >>= 1) m = fmaxf(m, __shfl_xor(m, off));
  if ((tid & 63) == 0) sred[tid >> 6] = m;
  __syncthreads();
  const float M = fmaxf(fmaxf(sred[0], sred[1]), fmaxf(sred[2], sred[3]));
  float s = 0.f;
  #pragma unroll
  for (int k = 0; k < 12; ++k) {
    int i = tid + k * 256;
    if (i < 3000) {
      v[k].x = __expf(v[k].x - M); v[k].y = __expf(v[k].y - M);
      v[k].z = __expf(v[k].z - M); v[k].w = __expf(v[k].w - M);
      s += v[k].x + v[k].y + v[k].z + v[k].w;
    }
  }
  #pragma unroll
  for (int off = 32; off; off >>= 1) s += __shfl_xor(s, off);
  __syncthreads();
  if ((tid & 63) == 0) sred[tid >> 6] = s;
  __syncthreads();
  const float inv = 1.f / (sred[0] + sred[1] + sred[2] + sred[3]);
  float4* ov = (float4*)row;
  #pragma unroll
  for (int k = 0; k < 12; ++k) {
    int i = tid + k * 256;
    if (i < 3000) {
      float4 x = v[k];
      x.x *= inv; x.y *= inv; x.z *= inv; x.w *= inv;
      ov[i] = x;
    }
  }
}

// ---------------- launch ----------------

extern "C" void kernel_launch(void* const* d_in, const int* in_sizes, int n_in,
                              void* d_out, int out_size, void* d_ws, size_t ws_size,
                              hipStream_t stream) {
  const int*   targets = (const int*)d_in[0];
  const float* options = (const float*)d_in[1];
  const float* h0      = (const float*)d_in[2];
  const float* c0      = (const float*)d_in[3];
  const float* emb     = (const float*)d_in[4];
  const float* W2      = (const float*)d_in[7];
  const float* Va      = (const float*)d_in[9];
  const float* Wx      = (const float*)d_in[11];
  const float* Wh      = (const float*)d_in[12];
  const float* bl      = (const float*)d_in[13];
  const float* Wd      = (const float*)d_in[14];
  const float* bd      = (const float*)d_in[15];

  float* out      = (float*)d_out;
  float* out_h    = out + N_PROBS;
  float* out_c    = out_h + (size_t)B * L;
  float* out_attn = out_c + (size_t)B * L;

  // ---- workspace layout (bytes), total ~31.1 MiB ----
  char* wsb = (char*)d_ws;
  float* v2     = (float*)(wsb);               // 4 KB
  float* wat    = (float*)(wsb + 4096);        // 8 KB
  float* ctx    = (float*)(wsb + 12288);       // 128 KB
  float* cx     = (float*)(wsb + 143360);      // 512 KB
  float* cst    = (float*)(wsb + 667648);      // 128 KB
  fp16*  hA     = (fp16*)(wsb + 798720);       // 64 KB
  fp16*  hB     = (fp16*)(wsb + 864256);       // 64 KB
  fp16*  Eg16   = (fp16*)(wsb + 1191936);      // 1 MB
  fp16*  Wx2t16 = (fp16*)(wsb + 2240512);      // 2 MB
  fp16*  Hb16   = (fp16*)(wsb + 1191936);      // alias X base, 4 MB (post pre-GEMM)
  fp16*  Whp    = (fp16*)(wsb + 7483392);      // 8 MB
  fp16*  prep   = (fp16*)(wsb + 15872000);     // 16 MB
  float* cxp    = (float*)(wsb + 15872000);    // alias prep (pre-GEMM phase only)
  fp16*  Wdt    = (fp16*)(wsb + 7483392);      // alias Whp+prep (post-recurrence)

  // attention (h-independent)
  k_v2<<<256, 256, 0, stream>>>(W2, Va, v2);
  k_score<<<512, 256, 0, stream>>>(options, v2, wat);
  k_attnctx<<<32, 256, 0, stream>>>(options, wat, out_attn, ctx);
  k_cx_part<<<512, 256, 0, stream>>>(ctx, Wx, cxp);
  k_cx_reduce<<<512, 256, 0, stream>>>(cxp, bl, cx);

  // transforms
  k_eg<<<2048, 256, 0, stream>>>(targets, emb, Eg16);
  k_wx2t<<<256, 256, 0, stream>>>(Wx, Wx2t16);
  k_whp<<<1024, 256, 0, stream>>>(Wh, Whp);

  // pre = Eg @ Wx2 + cx  (permuted prep layout)
  k_pre_mfma<<<512, 256, 0, stream>>>(Eg16, Wx2t16, cx, prep);
  k_h0split<<<128, 256, 0, stream>>>(h0, c0, hA, cst);

  // recurrence: per-step launches (R7 structure), finalize fused at t=63
  for (int t = 0; t < T; ++t) {
    const fp16* hin = (t & 1) ? hB : hA;
    fp16* hout = (t & 1) ? hA : hB;
    k_step4<<<256, 512, 0, stream>>>(Whp, prep, hin, hout, cst, Hb16,
                                     out_h, out_c, t);
  }

  // logits + softmax
  k_wdt<<<188 * 16, 256, 0, stream>>>(Wd, Wdt);
  k_logits_mfma<<<1504, 256, 0, stream>>>(Hb16, Wdt, bd, out);
  k_softmax<<<B * T, 256, 0, stream>>>(out);
}

// Round 15
// 541.244 us; speedup vs baseline: 1.0819x; 1.0114x over previous
//
#include <hip/hip_runtime.h>
#include <math.h>

// Decoder_910533066914 — R15: R14 (547us, best) + fused transform kernel.
// k_eg/k_wx2t/k_whp/k_h0split merged into one grid-partitioned launch
// (independent reads, disjoint writes). k_wdt stays after the recurrence
// (its output aliases Whp/prep). All math byte-identical to R14.

typedef _Float16 fp16;
typedef __attribute__((ext_vector_type(8))) _Float16 fp16x8;
typedef __attribute__((ext_vector_type(4))) _Float16 fp16x4;
typedef __attribute__((ext_vector_type(4))) float f32x4;

constexpr int B = 32, T = 64, S = 64, D = 1024, A = 512, E = 256, L = 1024, V = 12000;
constexpr int G = 4096;
constexpr size_t N_PROBS = (size_t)B * T * V;

__device__ inline void load_lds16(const void* g, void* l) {
  __builtin_amdgcn_global_load_lds(
      (const __attribute__((address_space(1))) unsigned int*)g,
      (__attribute__((address_space(3))) unsigned int*)l, 16, 0, 0);
}

// ---------------- attention precompute ----------------

__global__ void k_v2(const float* __restrict__ W2, const float* __restrict__ Va,
                     float* __restrict__ v2) {
  int gw = (blockIdx.x * blockDim.x + threadIdx.x) >> 6;
  int lane = threadIdx.x & 63;
  if (gw >= D) return;
  float acc = 0.f;
  for (int a = lane; a < A; a += 64) acc += W2[(size_t)gw * A + a] * Va[a];
  #pragma unroll
  for (int off = 32; off; off >>= 1) acc += __shfl_down(acc, off);
  if (lane == 0) v2[gw] = acc;
}

__global__ void k_score(const float* __restrict__ options, const float* __restrict__ v2,
                        float* __restrict__ w) {
  int row = (blockIdx.x * blockDim.x + threadIdx.x) >> 6;
  int lane = threadIdx.x & 63;
  if (row >= B * S) return;
  const float* orow = options + (size_t)row * D;
  float acc = 0.f;
  for (int d = lane; d < D; d += 64) acc += orow[d] * v2[d];
  #pragma unroll
  for (int off = 32; off; off >>= 1) acc += __shfl_down(acc, off);
  if (lane == 0) w[row] = acc;
}

__global__ __launch_bounds__(256) void k_attnctx(
    const float* __restrict__ options, const float* __restrict__ wat,
    float* __restrict__ oattn, float* __restrict__ ctx) {
  __shared__ float sw[64];
  const int b = blockIdx.x, tid = threadIdx.x;
  if (tid < 64) {
    float v = wat[b * 64 + tid];
    float m = v;
    #pragma unroll
    for (int off = 32; off; off >>= 1) m = fmaxf(m, __shfl_xor(m, off));
    float e = expf(v - m);
    float s = e;
    #pragma unroll
    for (int off = 32; off; off >>= 1) s += __shfl_xor(s, off);
    float res = e / s;
    sw[tid] = res;
    oattn[b * 64 + tid] = res;
  }
  __syncthreads();
  for (int d = tid; d < D; d += 256) {
    float acc = 0.f;
    #pragma unroll 8
    for (int s = 0; s < 64; ++s)
      acc += sw[s] * options[((size_t)(b * 64 + s)) * D + d];
    ctx[b * D + d] = acc;
  }
}

// ---------------- cx = bl + ctx@Wx1, split-K ----------------
__global__ __launch_bounds__(256) void k_cx_part(
    const float* __restrict__ ctx, const float* __restrict__ Wx,
    float* __restrict__ cxp) {
  const int jt = blockIdx.x & 15;
  const int bg = (blockIdx.x >> 4) & 3;
  const int kc = blockIdx.x >> 6;
  const int j = jt * 256 + threadIdx.x;
  const int b0 = bg * 8, d0 = kc * 128;
  float acc[8];
  #pragma unroll
  for (int bb = 0; bb < 8; ++bb) acc[bb] = 0.f;
  for (int d = 0; d < 128; ++d) {
    float wv = Wx[(size_t)(d0 + d) * G + j];
    #pragma unroll
    for (int bb = 0; bb < 8; ++bb)
      acc[bb] = fmaf(ctx[(b0 + bb) * D + d0 + d], wv, acc[bb]);
  }
  #pragma unroll
  for (int bb = 0; bb < 8; ++bb)
    cxp[((size_t)kc * 32 + b0 + bb) * G + j] = acc[bb];
}

__global__ void k_cx_reduce(const float* __restrict__ cxp, const float* __restrict__ bl,
                            float* __restrict__ cx) {
  int i = blockIdx.x * 256 + threadIdx.x;
  float s = bl[i & 4095];
  #pragma unroll
  for (int kc = 0; kc < 8; ++kc) s += cxp[(size_t)kc * 131072 + i];
  cx[i] = s;
}

// ---------------- fused transforms (grid-partitioned, one launch) -------------
// blocks [0,2048): eg gather; [2048,2304): wx2t; [2304,3328): whp; [3328,3456): h0split
__global__ __launch_bounds__(256) void k_xform(
    const int* __restrict__ targets, const float* __restrict__ emb,
    const float* __restrict__ Wx, const float* __restrict__ Wh,
    const float* __restrict__ h0, const float* __restrict__ c0,
    fp16* __restrict__ eg, fp16* __restrict__ wx2t16, fp16* __restrict__ whp,
    fp16* __restrict__ h16, float* __restrict__ cst) {
  __shared__ float s[64][65];
  const int bid = blockIdx.x;
  const int tid = threadIdx.x;

  if (bid < 2048) {            // ---- eg: emb gather -> fp16
    int tok = targets[bid];
    eg[(size_t)bid * E + tid] = (fp16)emb[(size_t)tok * E + tid];
    return;
  }
  if (bid < 2304) {            // ---- wx2t: Wx[D+e][j] -> [j][e] fp16
    const int lb = bid - 2048;
    const int et = lb >> 6, jt = lb & 63;
    const int e0 = et * 64, j0 = jt * 64;
    const int jj = tid & 63;
    #pragma unroll
    for (int k = 0; k < 16; ++k) {
      int ee = k * 4 + (tid >> 6);
      s[ee][jj] = Wx[(size_t)(D + e0 + ee) * G + j0 + jj];
    }
    __syncthreads();
    const int jc = tid >> 2, eq = tid & 3;
    fp16x8 o0, o1;
    #pragma unroll
    for (int i = 0; i < 8; ++i) {
      o0[i] = (fp16)s[eq * 16 + i][jc];
      o1[i] = (fp16)s[eq * 16 + 8 + i][jc];
    }
    size_t dst = (size_t)(j0 + jc) * E + e0 + eq * 16;
    *(fp16x8*)(wx2t16 + dst) = o0;
    *(fp16x8*)(wx2t16 + dst + 8) = o1;
    return;
  }
  if (bid < 3328) {            // ---- whp: Wh[l][col] -> [rowp][l] fp16
    const int lb = bid - 2304;
    const int lt = lb & 15, ct = lb >> 4;
    const int l0 = lt * 64, c0 = ct * 64;
    const int cc = tid & 63;
    #pragma unroll
    for (int k = 0; k < 16; ++k) {
      int ll = k * 4 + (tid >> 6);
      s[ll][cc] = Wh[(size_t)(l0 + ll) * G + c0 + cc];
    }
    __syncthreads();
    const int c = tid >> 2, lq = tid & 3;
    const int col = c0 + c, g = col >> 10, jj = col & 1023;
    const int rowp = ((jj >> 2) << 4) + (g << 2) + (jj & 3);
    fp16x8 o0, o1;
    #pragma unroll
    for (int i = 0; i < 8; ++i) {
      o0[i] = (fp16)s[lq * 16 + i][c];
      o1[i] = (fp16)s[lq * 16 + 8 + i][c];
    }
    size_t dst = (size_t)rowp * L + l0 + lq * 16;
    *(fp16x8*)(whp + dst) = o0;
    *(fp16x8*)(whp + dst + 8) = o1;
    return;
  }
  {                            // ---- h0split
    const int lb = bid - 3328;
    int i = lb * 256 + tid;
    h16[i] = (fp16)h0[i];
    cst[i] = c0[i];
  }
}

// ---------------- pre = Eg@Wx2t^T + cx -> prep[t][jb][b][jo*4+g] fp16 ---------
__global__ __launch_bounds__(256) void k_pre_mfma(
    const fp16* __restrict__ Ag, const fp16* __restrict__ Bg,
    const float* __restrict__ cx, fp16* __restrict__ prep) {
  __shared__ __align__(16) char lds[32768];
  char* sA = lds;
  char* sB = lds + 16384;
  const int bid = blockIdx.x;
  const int swz = (bid & 7) * 64 + (bid >> 3);
  const int mt = swz >> 5, nt = swz & 31;
  const int m0 = mt * 128, n0 = nt * 128;
  const int tid = threadIdx.x, w = tid >> 6, lane = tid & 63;
  const int wr = w >> 1, wc = w & 1;

  f32x4 acc[4][4];
  #pragma unroll
  for (int i = 0; i < 4; ++i)
    #pragma unroll
    for (int j = 0; j < 4; ++j) acc[i][j] = (f32x4){0.f, 0.f, 0.f, 0.f};

  int rowc[4], sloc[4];
  #pragma unroll
  for (int i = 0; i < 4; ++i) {
    int c = i * 4 + w;
    rowc[i] = c * 8 + (lane >> 3);
    sloc[i] = (lane & 7) ^ (rowc[i] & 7);
  }

  for (int kk = 0; kk < 4; ++kk) {
    if (kk) __syncthreads();
    const char* ga = (const char*)Ag + kk * 128;
    const char* gb = (const char*)Bg + kk * 128;
    #pragma unroll
    for (int i = 0; i < 4; ++i) {
      int c = i * 4 + w;
      load_lds16(ga + (size_t)(m0 + rowc[i]) * 512 + sloc[i] * 16, sA + c * 1024);
      load_lds16(gb + (size_t)(n0 + rowc[i]) * 512 + sloc[i] * 16, sB + c * 1024);
    }
    __syncthreads();
    #pragma unroll
    for (int ks = 0; ks < 2; ++ks) {
      fp16x8 av[4], bv[4];
      #pragma unroll
      for (int f = 0; f < 4; ++f) {
        int ra = wr * 64 + f * 16 + (lane & 15);
        int ca = (ks * 4 + (lane >> 4)) ^ (ra & 7);
        av[f] = *(const fp16x8*)(sA + ra * 128 + ca * 16);
        int rb = wc * 64 + f * 16 + (lane & 15);
        int cb = (ks * 4 + (lane >> 4)) ^ (rb & 7);
        bv[f] = *(const fp16x8*)(sB + rb * 128 + cb * 16);
      }
      #pragma unroll
      for (int fm = 0; fm < 4; ++fm)
        #pragma unroll
        for (int fn = 0; fn < 4; ++fn)
          acc[fm][fn] = __builtin_amdgcn_mfma_f32_16x16x32_f16(
              av[fm], bv[fn], acc[fm][fn], 0, 0, 0);
    }
  }

  const int r0o = m0 + wr * 64 + ((lane >> 4) << 2);
  const int c0o = n0 + wc * 64 + (lane & 15);
  #pragma unroll
  for (int fn = 0; fn < 4; ++fn) {
    int colg = c0o + fn * 16;
    int g = colg >> 10, jj = colg & 1023;
    int jb = jj >> 2, jo = jj & 3;
    #pragma unroll
    for (int fm = 0; fm < 4; ++fm) {
      #pragma unroll
      for (int r = 0; r < 4; ++r) {
        int row = r0o + fm * 16 + r;
        int b = row >> 6, t = row & 63;
        float v = acc[fm][fn][r] + cx[(size_t)b * G + colg];
        prep[(((size_t)t * 256 + jb) * 32 + b) * 16 + jo * 4 + g] = (fp16)v;
      }
    }
  }
}

// ---------------- recurrence step (R7's k_step4, finalize fused) --------------
__global__ __launch_bounds__(512) void k_step4(
    const fp16* __restrict__ Whp, const fp16* __restrict__ prep,
    const fp16* __restrict__ hin, fp16* __restrict__ hout,
    float* __restrict__ cst, fp16* __restrict__ Hb16,
    float* __restrict__ out_h, float* __restrict__ out_c, int t) {
  __shared__ float zred[8 * 2 * 64 * 4]; // 16 KB
  __shared__ float zf[32][16];           // 2 KB
  const int jb = blockIdx.x;
  const int tid = threadIdx.x;
  const int w = tid >> 6, lane = tid & 63;
  const int fr = lane & 15, kc = lane >> 4;

  float pf[4];
  float cprev = 0.f;
  const int gb = tid >> 2, gjo = tid & 3, gj = jb * 4 + gjo;
  if (tid < 128) {
    fp16x4 pv = *(const fp16x4*)(prep + (((size_t)t * 256 + jb) * 32 + gb) * 16 + gjo * 4);
    #pragma unroll
    for (int g = 0; g < 4; ++g) pf[g] = (float)pv[g];
    cprev = cst[gb * 1024 + gj];
  }

  f32x4 acc[2];
  acc[0] = (f32x4){0.f, 0.f, 0.f, 0.f};
  acc[1] = (f32x4){0.f, 0.f, 0.f, 0.f};
  const fp16* bb = Whp + (size_t)(jb * 16 + fr) * L;
  #pragma unroll
  for (int kk = 0; kk < 4; ++kk) {
    const int k0 = (w * 4 + kk) * 32 + kc * 8;
    fp16x8 bv = *(const fp16x8*)(bb + k0);
    #pragma unroll
    for (int m = 0; m < 2; ++m) {
      fp16x8 av = *(const fp16x8*)(hin + (size_t)(m * 16 + fr) * L + k0);
      acc[m] = __builtin_amdgcn_mfma_f32_16x16x32_f16(av, bv, acc[m], 0, 0, 0);
    }
  }
  #pragma unroll
  for (int m = 0; m < 2; ++m)
    *(f32x4*)&zred[((w * 2 + m) * 64 + lane) * 4] = acc[m];
  __syncthreads();
  {
    const int b = tid >> 4, c = tid & 15;
    const int lane2 = (((b & 15) >> 2) << 4) | c;
    const int reg = b & 3, m = b >> 4;
    float s = 0.f;
    #pragma unroll
    for (int ww = 0; ww < 8; ++ww)
      s += zred[((ww * 2 + m) * 64 + lane2) * 4 + reg];
    zf[b][c] = s;
  }
  __syncthreads();
  if (tid < 128) {
    float zi = zf[gb][gjo] + pf[0];
    float zff = zf[gb][4 + gjo] + pf[1];
    float zg = zf[gb][8 + gjo] + pf[2];
    float zo = zf[gb][12 + gjo] + pf[3];
    float si = 1.f / (1.f + expf(-zi));
    float sf = 1.f / (1.f + expf(-zff));
    float tg = tanhf(zg);
    float so = 1.f / (1.f + expf(-zo));
    float cn = sf * cprev + si * tg;
    float hn = so * tanhf(cn);
    const int hi_idx = gb * 1024 + gj;
    cst[hi_idx] = cn;
    hout[hi_idx] = (fp16)hn;
    Hb16[(size_t)(gb * 64 + t) * L + gj] = (fp16)hn;
    if (t == T - 1) {
      out_h[hi_idx] = hn;
      out_c[hi_idx] = cn;
    }
  }
}

// ---------------- Wd -> Wdt fp16 (after recurrence; output aliases Whp/prep) --
__global__ __launch_bounds__(256) void k_wdt(const float* __restrict__ Wd,
                                             fp16* __restrict__ Wdt) {
  __shared__ float s[64][65];
  const int lt = blockIdx.x & 15;
  const int vt = blockIdx.x >> 4;
  const int l0 = lt * 64, v0 = vt * 64;
  const int tid = threadIdx.x;
  const int lv = tid & 63;
  #pragma unroll
  for (int k = 0; k < 16; ++k) {
    int ll = k * 4 + (tid >> 6);
    int v = v0 + lv;
    s[ll][lv] = (v < V) ? Wd[(size_t)(l0 + ll) * V + v] : 0.f;
  }
  __syncthreads();
  const int vv = tid >> 2, lq = tid & 3;
  fp16x8 o0, o1;
  #pragma unroll
  for (int j = 0; j < 8; ++j) {
    o0[j] = (fp16)s[lq * 16 + j][vv];
    o1[j] = (fp16)s[lq * 16 + 8 + j][vv];
  }
  fp16* dst = Wdt + (size_t)(v0 + vv) * 1024 + l0 + lq * 16;
  *(fp16x8*)dst = o0;
  *(fp16x8*)(dst + 8) = o1;
}

// ---------------- logits fp16 MFMA GEMM, 32KB LDS, two-pass epilogue ---------
__global__ __launch_bounds__(256) void k_logits_mfma(
    const fp16* __restrict__ Ag, const fp16* __restrict__ Btg,
    const float* __restrict__ bd, float* __restrict__ out) {
  __shared__ __align__(16) char lds[32768];
  char* sA = lds;
  char* sB = lds + 16384;
  const int bid = blockIdx.x;
  const int wg = (bid & 7) * 188 + (bid >> 3);
  const int nt = wg >> 4, mt = wg & 15;   // column-major XCD coverage
  const int m0 = mt * 128, n0 = nt * 128;
  const int tid = threadIdx.x, w = tid >> 6, lane = tid & 63;
  const int wr = w >> 1, wc = w & 1;

  f32x4 acc[4][4];
  #pragma unroll
  for (int i = 0; i < 4; ++i)
    #pragma unroll
    for (int j = 0; j < 4; ++j) acc[i][j] = (f32x4){0.f, 0.f, 0.f, 0.f};

  int rowc[4], sloc[4];
  #pragma unroll
  for (int i = 0; i < 4; ++i) {
    int c = i * 4 + w;
    rowc[i] = c * 8 + (lane >> 3);
    sloc[i] = (lane & 7) ^ (rowc[i] & 7);
  }

  for (int kk = 0; kk < 16; ++kk) {
    if (kk) __syncthreads();
    const char* ga = (const char*)Ag + kk * 128;
    const char* gb = (const char*)Btg + kk * 128;
    #pragma unroll
    for (int i = 0; i < 4; ++i) {
      int c = i * 4 + w;
      load_lds16(ga + (size_t)(m0 + rowc[i]) * 2048 + sloc[i] * 16, sA + c * 1024);
      load_lds16(gb + (size_t)(n0 + rowc[i]) * 2048 + sloc[i] * 16, sB + c * 1024);
    }
    __syncthreads();
    #pragma unroll
    for (int ks = 0; ks < 2; ++ks) {
      fp16x8 av[4], bv[4];
      #pragma unroll
      for (int f = 0; f < 4; ++f) {
        int ra = wr * 64 + f * 16 + (lane & 15);
        int ca = (ks * 4 + (lane >> 4)) ^ (ra & 7);
        av[f] = *(const fp16x8*)(sA + ra * 128 + ca * 16);
        int rb = wc * 64 + f * 16 + (lane & 15);
        int cb = (ks * 4 + (lane >> 4)) ^ (rb & 7);
        bv[f] = *(const fp16x8*)(sB + rb * 128 + cb * 16);
      }
      #pragma unroll
      for (int fm = 0; fm < 4; ++fm)
        #pragma unroll
        for (int fn = 0; fn < 4; ++fn)
          acc[fm][fn] = __builtin_amdgcn_mfma_f32_16x16x32_f16(
              av[fm], bv[fn], acc[fm][fn], 0, 0, 0);
    }
  }

  // two-pass epilogue: 64x128 fp32 half-tile in the 32KB LDS, coalesced out
  float* ctile = (float*)lds;
  float bvv[4];
  #pragma unroll
  for (int fn = 0; fn < 4; ++fn) {
    int colg = n0 + wc * 64 + fn * 16 + (lane & 15);
    bvv[fn] = (colg < V) ? bd[colg] : 0.f;
  }
  #pragma unroll
  for (int p = 0; p < 2; ++p) {
    __syncthreads();
    if (wr == p) {
      const int col = wc * 64 + (lane & 15);
      #pragma unroll
      for (int fn = 0; fn < 4; ++fn) {
        #pragma unroll
        for (int fm = 0; fm < 4; ++fm) {
          int row = fm * 16 + ((lane >> 4) << 2);
          #pragma unroll
          for (int r = 0; r < 4; ++r)
            ctile[(row + r) * 128 + col + fn * 16] = acc[fm][fn][r] + bvv[fn];
        }
      }
    }
    __syncthreads();
    #pragma unroll
    for (int it = 0; it < 8; ++it) {
      int idx = it * 256 + tid;
      int row = idx >> 5, ch = idx & 31;
      int colg = n0 + ch * 4;
      if (colg < V)
        *(float4*)&out[(size_t)(m0 + p * 64 + row) * V + colg] =
            *(float4*)&ctile[row * 128 + ch * 4];
    }
  }
}

// ---------------- row softmax (register-resident) ----------------
__global__ __launch_bounds__(256) void k_softmax(float* __restrict__ logits) {
  __shared__ float sred[4];
  float* row = logits + (size_t)blockIdx.x * V;
  const int tid = threadIdx.x;
  const float4* rv = (const float4*)row;
  float4 v[12];
  float m = -3.4e38f;
  #pragma unroll
  for (int k = 0; k < 12; ++k) {
    int i = tid + k * 256;
    if (i < 3000) {
      v[k] = rv[i];
      m = fmaxf(fmaxf(m, fmaxf(v[k].x, v[k].y)), fmaxf(v[k].z, v[k].w));
    }
  }
  #pragma unroll
  for (int off = 32; off; off >>= 1) m = fmaxf(m, __shfl_xor(m, off));
  if ((tid & 63) == 0) sred[tid >> 6] = m;
  __syncthreads();
  const float M = fmaxf(fmaxf(sred[0], sred[1]), fmaxf(sred[2], sred[3]));
  float s = 0.f;
  #pragma unroll
  for (int k = 0; k < 12; ++k) {
    int i = tid + k * 256;
    if (i < 3000) {
      v[k].x = __expf(v[k].x - M); v[k].y = __expf(v[k].y - M);
      v[k].z = __expf(v[k].z - M); v[k].w = __expf(v[k].w - M);
      s += v[k].x + v[k].y + v[k].z + v[k].w;
    }
  }
  #pragma unroll
  for (int off = 32; off; off >>= 1) s += __shfl_xor(s, off);
  __syncthreads();
  if ((tid & 63) == 0) sred[tid >> 6] = s;
  __syncthreads();
  const float inv = 1.f / (sred[0] + sred[1] + sred[2] + sred[3]);
  float4* ov = (float4*)row;
  #pragma unroll
  for (int k = 0; k < 12; ++k) {
    int i = tid + k * 256;
    if (i < 3000) {
      float4 x = v[k];
      x.x *= inv; x.y *= inv; x.z *= inv; x.w *= inv;
      ov[i] = x;
    }
  }
}

// ---------------- launch ----------------

extern "C" void kernel_launch(void* const* d_in, const int* in_sizes, int n_in,
                              void* d_out, int out_size, void* d_ws, size_t ws_size,
                              hipStream_t stream) {
  const int*   targets = (const int*)d_in[0];
  const float* options = (const float*)d_in[1];
  const float* h0      = (const float*)d_in[2];
  const float* c0      = (const float*)d_in[3];
  const float* emb     = (const float*)d_in[4];
  const float* W2      = (const float*)d_in[7];
  const float* Va      = (const float*)d_in[9];
  const float* Wx      = (const float*)d_in[11];
  const float* Wh      = (const float*)d_in[12];
  const float* bl      = (const float*)d_in[13];
  const float* Wd      = (const float*)d_in[14];
  const float* bd      = (const float*)d_in[15];

  float* out      = (float*)d_out;
  float* out_h    = out + N_PROBS;
  float* out_c    = out_h + (size_t)B * L;
  float* out_attn = out_c + (size_t)B * L;

  // ---- workspace layout (bytes), total ~31.1 MiB ----
  char* wsb = (char*)d_ws;
  float* v2     = (float*)(wsb);               // 4 KB
  float* wat    = (float*)(wsb + 4096);        // 8 KB
  float* ctx    = (float*)(wsb + 12288);       // 128 KB
  float* cx     = (float*)(wsb + 143360);      // 512 KB
  float* cst    = (float*)(wsb + 667648);      // 128 KB
  fp16*  hA     = (fp16*)(wsb + 798720);       // 64 KB
  fp16*  hB     = (fp16*)(wsb + 864256);       // 64 KB
  fp16*  Eg16   = (fp16*)(wsb + 1191936);      // 1 MB
  fp16*  Wx2t16 = (fp16*)(wsb + 2240512);      // 2 MB
  fp16*  Hb16   = (fp16*)(wsb + 1191936);      // alias X base, 4 MB (post pre-GEMM)
  fp16*  Whp    = (fp16*)(wsb + 7483392);      // 8 MB
  fp16*  prep   = (fp16*)(wsb + 15872000);     // 16 MB
  float* cxp    = (float*)(wsb + 15872000);    // alias prep (pre-GEMM phase only)
  fp16*  Wdt    = (fp16*)(wsb + 7483392);      // alias Whp+prep (post-recurrence)

  // attention (h-independent)
  k_v2<<<256, 256, 0, stream>>>(W2, Va, v2);
  k_score<<<512, 256, 0, stream>>>(options, v2, wat);
  k_attnctx<<<32, 256, 0, stream>>>(options, wat, out_attn, ctx);
  k_cx_part<<<512, 256, 0, stream>>>(ctx, Wx, cxp);
  k_cx_reduce<<<512, 256, 0, stream>>>(cxp, bl, cx);

  // fused transforms (eg + wx2t + whp + h0split), one launch
  k_xform<<<3456, 256, 0, stream>>>(targets, emb, Wx, Wh, h0, c0,
                                    Eg16, Wx2t16, Whp, hA, cst);

  // pre = Eg @ Wx2 + cx  (permuted prep layout)
  k_pre_mfma<<<512, 256, 0, stream>>>(Eg16, Wx2t16, cx, prep);

  // recurrence: per-step launches (R7 structure), finalize fused at t=63
  for (int t = 0; t < T; ++t) {
    const fp16* hin = (t & 1) ? hB : hA;
    fp16* hout = (t & 1) ? hA : hB;
    k_step4<<<256, 512, 0, stream>>>(Whp, prep, hin, hout, cst, Hb16,
                                     out_h, out_c, t);
  }

  // logits + softmax
  k_wdt<<<188 * 16, 256, 0, stream>>>(Wd, Wdt);
  k_logits_mfma<<<1504, 256, 0, stream>>>(Hb16, Wdt, bd, out);
  k_softmax<<<B * T, 256, 0, stream>>>(out);
}